// Round 1
// baseline (513.938 us; speedup 1.0000x reference)
//
#include <hip/hip_runtime.h>
#include <hip/hip_bf16.h>

// IO-HMM fwd/bwd chain + projection for MI355X (gfx950).
// L=256 steps, B=128 batch, S=256 states, NL=64 labels.
//
// Kernel 1: 16 blocks (8 fwd, 8 bwd) x 256 threads (4 waves).
//   Each block owns 16 batches for the full chain. Each wave owns M=64 states
//   with T held in registers as MFMA A-fragments (bf16 hi/lo split).
//   Carry (16 b x 256 k) lives in LDS, double-buffered, bf16 hi/lo planes,
//   row stride 288 bf16 (144 words == 16 mod 32 -> conflict-free b128 frags).
//   3-product split MFMA (hh + hl + lh) == ~fp32 precision per step.
// Kernel 2: 512 blocks; p = fw*g staged to LDS (bf16 hi/lo), output matrix
//   held as split B-fragments in registers; 3-product MFMA; scattered stores.

typedef __bf16 bf16x8 __attribute__((ext_vector_type(8)));
typedef __bf16 bf16x4 __attribute__((ext_vector_type(4)));
typedef float  f32x4  __attribute__((ext_vector_type(4)));

#define LL 256
#define BB 128
#define SS 256
#define BT 16
#define KSTR 288   // carry row stride in bf16 units

__device__ __forceinline__ f32x4 mfma16(bf16x8 a, bf16x8 b, f32x4 c) {
  return __builtin_amdgcn_mfma_f32_16x16x32_bf16(a, b, c, 0, 0, 0);
}

__global__ __launch_bounds__(256, 1)
void hmm_chain(const int* __restrict__ sent, const float* __restrict__ emb,
               const float* __restrict__ T, float* __restrict__ fwbuf,
               float* __restrict__ gbuf)
{
  __shared__ __bf16 s_carry[2][2][BT][KSTR]; // [buf][hi/lo][batch][k]
  __shared__ int s_tok[BT * 257];            // [batch][l], stride 257

  const int tid  = threadIdx.x;
  const int lane = tid & 63;
  const int w    = tid >> 6;   // wave 0..3 -> states [64w, 64w+64)
  const int m    = lane & 15;  // A row-in-tile / B col (= batch)
  const int q    = lane >> 4;  // quad

  const int  bid = blockIdx.x;
  const bool fwd = (bid < 8);
  const int  bg0 = (fwd ? bid : bid - 8) * BT;

  // ---- stage sentence tokens ----
  for (int idx = tid; idx < BT * LL; idx += 256) {
    int bb = idx >> 8, l2 = idx & 255;
    s_tok[bb * 257 + l2] = sent[(bg0 + bb) * LL + l2];
  }
  __syncthreads();

  // ---- load T fragments (A operand), split bf16 hi/lo ----
  bf16x8 a_hi[4][8], a_lo[4][8];
#pragma unroll
  for (int mt = 0; mt < 4; ++mt) {
#pragma unroll
    for (int kt = 0; kt < 8; ++kt) {
      const int r0 = 64 * w + 16 * mt + m;   // state (M index)
      const int kb = 32 * kt + 8 * q;        // k base
      float v[8];
      if (fwd) {
        f32x4 f0 = *(const f32x4*)(T + r0 * 256 + kb);
        f32x4 f1 = *(const f32x4*)(T + r0 * 256 + kb + 4);
#pragma unroll
        for (int j = 0; j < 4; ++j) { v[j] = f0[j]; v[4 + j] = f1[j]; }
      } else {
#pragma unroll
        for (int j = 0; j < 8; ++j) v[j] = T[(kb + j) * 256 + r0]; // T^T
      }
      bf16x8 hi, lo;
#pragma unroll
      for (int j = 0; j < 8; ++j) {
        __bf16 h = (__bf16)v[j];
        hi[j] = h;
        lo[j] = (__bf16)(v[j] - (float)h);
      }
      a_hi[mt][kt] = hi; a_lo[mt][kt] = lo;
    }
  }

  // ---- init carry at l0 ----
  const int l0 = fwd ? 0 : (LL - 1);
  {
    const int tok0 = s_tok[m * 257 + l0];
#pragma unroll
    for (int mt = 0; mt < 4; ++mt) {
      const int st = 64 * w + 16 * mt + 4 * q;
      f32x4 e0 = *(const f32x4*)(emb + (size_t)tok0 * 256 + st);
      f32x4 outv = e0;
      if (!fwd) outv = 1.0f;  // g[L-1] = 1
      float* dst = (fwd ? fwbuf : gbuf) + ((size_t)(l0 * BB + bg0 + m)) * 256 + st;
      *(f32x4*)dst = outv;
      bf16x4 h4, l4;
#pragma unroll
      for (int r = 0; r < 4; ++r) {
        __bf16 h = (__bf16)e0[r];
        h4[r] = h;
        l4[r] = (__bf16)(e0[r] - (float)h);
      }
      *(bf16x4*)&s_carry[0][0][m][st] = h4;
      *(bf16x4*)&s_carry[0][1][m][st] = l4;
    }
  }

  // ---- prefetch em for first step ----
  f32x4 em_pref[4];
  {
    const int l1 = fwd ? 1 : (LL - 2);
    const int tok1 = s_tok[m * 257 + l1];
#pragma unroll
    for (int mt = 0; mt < 4; ++mt)
      em_pref[mt] = *(const f32x4*)(emb + (size_t)tok1 * 256 + 64 * w + 16 * mt + 4 * q);
  }
  __syncthreads();

  // ---- main chain ----
  for (int s = 1; s < LL; ++s) {
    const int l  = fwd ? s : (LL - 1) - s;
    const int rb = (s - 1) & 1, wb = s & 1;

    // B fragments: full carry, hi+lo planes
    bf16x8 bhi[8], blo[8];
#pragma unroll
    for (int kt = 0; kt < 8; ++kt) {
      bhi[kt] = *(const bf16x8*)&s_carry[rb][0][m][32 * kt + 8 * q];
      blo[kt] = *(const bf16x8*)&s_carry[rb][1][m][32 * kt + 8 * q];
    }

    f32x4 acc0[4], acc1[4];
#pragma unroll
    for (int mt = 0; mt < 4; ++mt) { acc0[mt] = 0.0f; acc1[mt] = 0.0f; }
#pragma unroll
    for (int kt = 0; kt < 8; ++kt) {
#pragma unroll
      for (int mt = 0; mt < 4; ++mt) {
        acc0[mt] = mfma16(a_hi[mt][kt], bhi[kt], acc0[mt]);
        acc1[mt] = mfma16(a_hi[mt][kt], blo[kt], acc1[mt]);
        acc1[mt] = mfma16(a_lo[mt][kt], bhi[kt], acc1[mt]);
      }
    }

    // consume prefetched em, then issue next prefetch
    f32x4 em_now[4];
#pragma unroll
    for (int mt = 0; mt < 4; ++mt) em_now[mt] = em_pref[mt];
    {
      const int ln = fwd ? (s + 1 < LL ? s + 1 : LL - 1)
                         : ((LL - 2) - s > 0 ? (LL - 2) - s : 0);
      const int tokn = s_tok[m * 257 + ln];
#pragma unroll
      for (int mt = 0; mt < 4; ++mt)
        em_pref[mt] = *(const f32x4*)(emb + (size_t)tokn * 256 + 64 * w + 16 * mt + 4 * q);
    }

    // epilogue: combine, scale by em, store, split back to LDS
#pragma unroll
    for (int mt = 0; mt < 4; ++mt) {
      const int st = 64 * w + 16 * mt + 4 * q;
      f32x4 v  = acc0[mt] + acc1[mt];  // pre-em matmul result
      f32x4 cn = v * em_now[mt];       // new carry
      f32x4 sv = fwd ? cn : v;         // fwd stores fw[l]; bwd stores g[l]=v
      *(f32x4*)((fwd ? fwbuf : gbuf) + ((size_t)(l * BB + bg0 + m)) * 256 + st) = sv;
      bf16x4 h4, l4;
#pragma unroll
      for (int r = 0; r < 4; ++r) {
        __bf16 h = (__bf16)cn[r];
        h4[r] = h;
        l4[r] = (__bf16)(cn[r] - (float)h);
      }
      *(bf16x4*)&s_carry[wb][0][m][st] = h4;
      *(bf16x4*)&s_carry[wb][1][m][st] = l4;
    }
    __syncthreads();
  }
}

__global__ __launch_bounds__(256, 1)
void hmm_score(const float* __restrict__ fwbuf, const float* __restrict__ gbuf,
               const float* __restrict__ outm, float* __restrict__ score)
{
  __shared__ __bf16 p_hi[64][256];
  __shared__ __bf16 p_lo[64][256];

  const int tid  = threadIdx.x;
  const int lane = tid & 63;
  const int w    = tid >> 6;
  const int m    = lane & 15;
  const int q    = lane >> 4;
  const int R0   = blockIdx.x * 64;  // row = l*128 + b

  // out matrix as split B fragments in registers (L2-hot, tiny)
  bf16x8 o_hi[8][4], o_lo[8][4];
#pragma unroll
  for (int kt = 0; kt < 8; ++kt) {
#pragma unroll
    for (int nt = 0; nt < 4; ++nt) {
      bf16x8 hi, lo;
#pragma unroll
      for (int j = 0; j < 8; ++j) {
        float vv = outm[(32 * kt + 8 * q + j) * 64 + 16 * nt + m];
        __bf16 h = (__bf16)vv;
        hi[j] = h;
        lo[j] = (__bf16)(vv - (float)h);
      }
      o_hi[kt][nt] = hi; o_lo[kt][nt] = lo;
    }
  }

  // stage p = fw * g as split bf16
  for (int idx = tid; idx < 64 * 64; idx += 256) {
    int row = idx >> 6, c4 = (idx & 63) * 4;
    f32x4 f = *(const f32x4*)(fwbuf + ((size_t)(R0 + row)) * 256 + c4);
    f32x4 gg = *(const f32x4*)(gbuf + ((size_t)(R0 + row)) * 256 + c4);
    f32x4 p = f * gg;
    bf16x4 h4, l4;
#pragma unroll
    for (int r = 0; r < 4; ++r) {
      __bf16 h = (__bf16)p[r];
      h4[r] = h;
      l4[r] = (__bf16)(p[r] - (float)h);
    }
    *(bf16x4*)&p_hi[row][c4] = h4;
    *(bf16x4*)&p_lo[row][c4] = l4;
  }
  __syncthreads();

  f32x4 acc0[4], acc1[4];
#pragma unroll
  for (int nt = 0; nt < 4; ++nt) { acc0[nt] = 0.0f; acc1[nt] = 0.0f; }
#pragma unroll
  for (int kt = 0; kt < 8; ++kt) {
    bf16x8 ph = *(const bf16x8*)&p_hi[16 * w + m][32 * kt + 8 * q];
    bf16x8 pl = *(const bf16x8*)&p_lo[16 * w + m][32 * kt + 8 * q];
#pragma unroll
    for (int nt = 0; nt < 4; ++nt) {
      acc0[nt] = mfma16(ph, o_hi[kt][nt], acc0[nt]);
      acc1[nt] = mfma16(ph, o_lo[kt][nt], acc1[nt]);
      acc1[nt] = mfma16(pl, o_hi[kt][nt], acc1[nt]);
    }
  }

#pragma unroll
  for (int nt = 0; nt < 4; ++nt) {
    f32x4 v = acc0[nt] + acc1[nt];
#pragma unroll
    for (int r = 0; r < 4; ++r) {
      int row = R0 + 16 * w + 4 * q + r;
      int l = row >> 7, b = row & 127;
      score[(size_t)b * 16384 + l * 64 + 16 * nt + m] = v[r];
    }
  }
}

extern "C" void kernel_launch(void* const* d_in, const int* in_sizes, int n_in,
                              void* d_out, int out_size, void* d_ws, size_t ws_size,
                              hipStream_t stream) {
  (void)in_sizes; (void)n_in; (void)out_size; (void)ws_size;
  const int*   sent = (const int*)d_in[0];
  const float* emb  = (const float*)d_in[1];
  const float* T    = (const float*)d_in[2];
  const float* outm = (const float*)d_in[3];
  float* fw = (float*)d_ws;                         // [L][B][S] fp32, 32 MB
  float* g  = fw + (size_t)LL * BB * SS;            // [L][B][S] fp32, 32 MB

  hmm_chain<<<16, 256, 0, stream>>>(sent, emb, T, fw, g);
  hmm_score<<<512, 256, 0, stream>>>(fw, g, outm, (float*)d_out);
}

// Round 2
// 456.775 us; speedup vs baseline: 1.1251x; 1.1251x over previous
//
#include <hip/hip_runtime.h>
#include <hip/hip_bf16.h>

// IO-HMM fwd/bwd chain + projection for MI355X (gfx950).
// L=256 steps, B=128 batch, S=256 states, NL=64 labels.
//
// Kernel 1 (chain): 16 blocks (8 fwd, 8 bwd) x 512 threads (8 waves).
//   Each block owns 16 batches for the full chain; wave w owns 32 states
//   [32w,32w+32) with T held in registers as MFMA A-fragments, bf16 hi/lo
//   split (128 VGPR/lane -- fits, no spill; round-1's M=64 needed 256 VGPR
//   for A alone and spilled every step).
//   Carry (16 b x 256 k) in LDS, double-buffered, bf16 hi/lo planes.
//   Per-step barrier is raw `s_waitcnt lgkmcnt(0); s_barrier` -- only LDS
//   ordering is needed; __syncthreads would drain vmcnt(0) (em gathers +
//   global stores) on the critical path every step.
//   3-product split MFMA (hh + hl + lh) ~ fp32 precision per step.
// Kernel 2 (score): 512 blocks x 256 threads; wave w owns n-tile w so the
//   output-matrix fragments are only 16 regs (64 VGPR -- round-1 held all
//   4 n-tiles = 256 VGPR and spilled); p = fw*g staged in LDS hi/lo.

typedef __bf16 bf16x8 __attribute__((ext_vector_type(8)));
typedef __bf16 bf16x4 __attribute__((ext_vector_type(4)));
typedef float  f32x4  __attribute__((ext_vector_type(4)));

#define LL 256
#define BB 128
#define SS 256
#define BT 16
#define KSTR 288   // carry row stride in bf16 units (16B-aligned rows)

static __device__ __forceinline__ f32x4 mfma16(bf16x8 a, bf16x8 b, f32x4 c) {
  return __builtin_amdgcn_mfma_f32_16x16x32_bf16(a, b, c, 0, 0, 0);
}

// LDS-only barrier: order ds ops, leave vmcnt in flight.
static __device__ __forceinline__ void lds_barrier() {
  __asm__ __volatile__("s_waitcnt lgkmcnt(0)\n\ts_barrier" ::: "memory");
}

__global__ __launch_bounds__(512, 2)
void hmm_chain(const int* __restrict__ sent, const float* __restrict__ emb,
               const float* __restrict__ T, float* __restrict__ fwbuf,
               float* __restrict__ gbuf)
{
  __shared__ __bf16 s_carry[2][2][BT][KSTR]; // [buf][hi/lo][batch][k]
  __shared__ int s_tok[BT * 257];            // [batch][l], stride 257

  const int tid  = threadIdx.x;
  const int lane = tid & 63;
  const int w    = tid >> 6;   // wave 0..7 -> states [32w, 32w+32)
  const int m    = lane & 15;  // A row-in-tile / B col (= batch)
  const int q    = lane >> 4;  // quad

  const int  bid = blockIdx.x;
  const bool fwd = (bid < 8);
  const int  bg0 = (fwd ? bid : bid - 8) * BT;
  float* const obuf = fwd ? fwbuf : gbuf;

  // ---- stage sentence tokens ----
  for (int idx = tid; idx < BT * LL; idx += 512) {
    int bb = idx >> 8, l2 = idx & 255;
    s_tok[bb * 257 + l2] = sent[(bg0 + bb) * LL + l2];
  }
  __syncthreads();

  // ---- load T fragments (A operand), split bf16 hi/lo: 32 frags = 128 VGPR
  bf16x8 a_hi[2][8], a_lo[2][8];
#pragma unroll
  for (int mt = 0; mt < 2; ++mt) {
#pragma unroll
    for (int kt = 0; kt < 8; ++kt) {
      const int r0 = 32 * w + 16 * mt + m;   // state (M index)
      const int kb = 32 * kt + 8 * q;        // k base
      float v[8];
      if (fwd) {
        f32x4 f0 = *(const f32x4*)(T + r0 * 256 + kb);
        f32x4 f1 = *(const f32x4*)(T + r0 * 256 + kb + 4);
#pragma unroll
        for (int j = 0; j < 4; ++j) { v[j] = f0[j]; v[4 + j] = f1[j]; }
      } else {
#pragma unroll
        for (int j = 0; j < 8; ++j) v[j] = T[(kb + j) * 256 + r0]; // T^T
      }
      bf16x8 hi, lo;
#pragma unroll
      for (int j = 0; j < 8; ++j) {
        __bf16 h = (__bf16)v[j];
        hi[j] = h;
        lo[j] = (__bf16)(v[j] - (float)h);
      }
      a_hi[mt][kt] = hi; a_lo[mt][kt] = lo;
    }
  }

  // ---- init carry at l0 ----
  const int l0 = fwd ? 0 : (LL - 1);
  {
    const int tok0 = s_tok[m * 257 + l0];
#pragma unroll
    for (int mt = 0; mt < 2; ++mt) {
      const int st = 32 * w + 16 * mt + 4 * q;
      f32x4 e0 = *(const f32x4*)(emb + (size_t)tok0 * 256 + st);
      f32x4 outv = e0;
      if (!fwd) outv = 1.0f;  // g[L-1] = 1
      *(f32x4*)(obuf + ((size_t)(l0 * BB + bg0 + m)) * 256 + st) = outv;
      bf16x4 h4, l4;
#pragma unroll
      for (int r = 0; r < 4; ++r) {
        __bf16 h = (__bf16)e0[r];
        h4[r] = h;
        l4[r] = (__bf16)(e0[r] - (float)h);
      }
      *(bf16x4*)&s_carry[0][0][m][st] = h4;
      *(bf16x4*)&s_carry[0][1][m][st] = l4;
    }
  }

  // ---- prefetch em for first step ----
  f32x4 em_pref[2];
  {
    const int l1 = fwd ? 1 : (LL - 2);
    const int tok1 = s_tok[m * 257 + l1];
#pragma unroll
    for (int mt = 0; mt < 2; ++mt)
      em_pref[mt] = *(const f32x4*)(emb + (size_t)tok1 * 256 + 32 * w + 16 * mt + 4 * q);
  }
  __syncthreads();

  // ---- main chain ----
  for (int s = 1; s < LL; ++s) {
    const int l  = fwd ? s : (LL - 1) - s;
    const int rb = (s - 1) & 1, wb = s & 1;

    // B hi-plane preloaded (32 VGPR); lo-plane streamed inside the loop
    bf16x8 bhi[8];
#pragma unroll
    for (int kt = 0; kt < 8; ++kt)
      bhi[kt] = *(const bf16x8*)&s_carry[rb][0][m][32 * kt + 8 * q];

    f32x4 acc[2];
#pragma unroll
    for (int mt = 0; mt < 2; ++mt) acc[mt] = 0.0f;
#pragma unroll
    for (int kt = 0; kt < 8; ++kt) {
      bf16x8 blo = *(const bf16x8*)&s_carry[rb][1][m][32 * kt + 8 * q];
#pragma unroll
      for (int mt = 0; mt < 2; ++mt) {
        acc[mt] = mfma16(a_hi[mt][kt], bhi[kt], acc[mt]);
        acc[mt] = mfma16(a_hi[mt][kt], blo,     acc[mt]);
        acc[mt] = mfma16(a_lo[mt][kt], bhi[kt], acc[mt]);
      }
    }

    // consume prefetched em, then issue next prefetch
    f32x4 em_now[2];
#pragma unroll
    for (int mt = 0; mt < 2; ++mt) em_now[mt] = em_pref[mt];
    {
      const int ln = fwd ? (s + 1 < LL ? s + 1 : LL - 1)
                         : ((LL - 2) - s > 0 ? (LL - 2) - s : 0);
      const int tokn = s_tok[m * 257 + ln];
#pragma unroll
      for (int mt = 0; mt < 2; ++mt)
        em_pref[mt] = *(const f32x4*)(emb + (size_t)tokn * 256 + 32 * w + 16 * mt + 4 * q);
    }

    // epilogue: scale by em, store, split back to LDS
#pragma unroll
    for (int mt = 0; mt < 2; ++mt) {
      const int st = 32 * w + 16 * mt + 4 * q;
      f32x4 v  = acc[mt];              // pre-em matmul result
      f32x4 cn = v * em_now[mt];       // new carry
      f32x4 sv = fwd ? cn : v;         // fwd stores fw[l]; bwd stores g[l]=v
      *(f32x4*)(obuf + ((size_t)(l * BB + bg0 + m)) * 256 + st) = sv;
      bf16x4 h4, l4;
#pragma unroll
      for (int r = 0; r < 4; ++r) {
        __bf16 h = (__bf16)cn[r];
        h4[r] = h;
        l4[r] = (__bf16)(cn[r] - (float)h);
      }
      *(bf16x4*)&s_carry[wb][0][m][st] = h4;
      *(bf16x4*)&s_carry[wb][1][m][st] = l4;
    }
    lds_barrier();  // LDS ordering only; global stores/loads stay in flight
  }
}

__global__ __launch_bounds__(256, 1)
void hmm_score(const float* __restrict__ fwbuf, const float* __restrict__ gbuf,
               const float* __restrict__ outm, float* __restrict__ score)
{
  __shared__ __bf16 p_hi[64][272];
  __shared__ __bf16 p_lo[64][272];

  const int tid  = threadIdx.x;
  const int lane = tid & 63;
  const int w    = tid >> 6;   // wave = n-tile (labels [16w,16w+16))
  const int m    = lane & 15;
  const int q    = lane >> 4;
  const int R0   = blockIdx.x * 64;  // row = l*128 + b

  // out matrix fragments for THIS wave's n-tile only: 16 frags = 64 VGPR
  bf16x8 o_hi[8], o_lo[8];
#pragma unroll
  for (int kt = 0; kt < 8; ++kt) {
    bf16x8 hi, lo;
#pragma unroll
    for (int j = 0; j < 8; ++j) {
      float vv = outm[(32 * kt + 8 * q + j) * 64 + 16 * w + m];
      __bf16 h = (__bf16)vv;
      hi[j] = h;
      lo[j] = (__bf16)(vv - (float)h);
    }
    o_hi[kt] = hi; o_lo[kt] = lo;
  }

  // stage p = fw * g as split bf16 (coalesced row loads)
  for (int idx = tid; idx < 64 * 64; idx += 256) {
    int row = idx >> 6, c4 = (idx & 63) * 4;
    f32x4 f  = *(const f32x4*)(fwbuf + ((size_t)(R0 + row)) * 256 + c4);
    f32x4 gg = *(const f32x4*)(gbuf  + ((size_t)(R0 + row)) * 256 + c4);
    f32x4 p = f * gg;
    bf16x4 h4, l4;
#pragma unroll
    for (int r = 0; r < 4; ++r) {
      __bf16 h = (__bf16)p[r];
      h4[r] = h;
      l4[r] = (__bf16)(p[r] - (float)h);
    }
    *(bf16x4*)&p_hi[row][c4] = h4;
    *(bf16x4*)&p_lo[row][c4] = l4;
  }
  __syncthreads();

  f32x4 acc[4];
#pragma unroll
  for (int mt = 0; mt < 4; ++mt) acc[mt] = 0.0f;
#pragma unroll
  for (int kt = 0; kt < 8; ++kt) {
#pragma unroll
    for (int mt = 0; mt < 4; ++mt) {
      bf16x8 ph = *(const bf16x8*)&p_hi[16 * mt + m][32 * kt + 8 * q];
      bf16x8 pl = *(const bf16x8*)&p_lo[16 * mt + m][32 * kt + 8 * q];
      acc[mt] = mfma16(ph, o_hi[kt], acc[mt]);
      acc[mt] = mfma16(ph, o_lo[kt], acc[mt]);
      acc[mt] = mfma16(pl, o_hi[kt], acc[mt]);
    }
  }

#pragma unroll
  for (int mt = 0; mt < 4; ++mt) {
#pragma unroll
    for (int r = 0; r < 4; ++r) {
      int row = R0 + 16 * mt + 4 * q + r;
      int l = row >> 7, b = row & 127;
      score[(size_t)b * 16384 + l * 64 + 16 * w + m] = acc[mt][r];
    }
  }
}

extern "C" void kernel_launch(void* const* d_in, const int* in_sizes, int n_in,
                              void* d_out, int out_size, void* d_ws, size_t ws_size,
                              hipStream_t stream) {
  (void)in_sizes; (void)n_in; (void)out_size; (void)ws_size;
  const int*   sent = (const int*)d_in[0];
  const float* emb  = (const float*)d_in[1];
  const float* T    = (const float*)d_in[2];
  const float* outm = (const float*)d_in[3];
  float* fw = (float*)d_ws;                         // [L][B][S] fp32, 32 MB
  float* g  = fw + (size_t)LL * BB * SS;            // [L][B][S] fp32, 32 MB

  hmm_chain<<<16, 512, 0, stream>>>(sent, emb, T, fw, g);
  hmm_score<<<512, 256, 0, stream>>>(fw, g, outm, (float*)d_out);
}

// Round 3
// 422.953 us; speedup vs baseline: 1.2151x; 1.0800x over previous
//
#include <hip/hip_runtime.h>
#include <hip/hip_bf16.h>

// IO-HMM fwd/bwd chain + projection for MI355X (gfx950).
// L=256 steps, B=128 batch, S=256 states, NL=64 labels.
//
// Kernel 1 (chain): 16 blocks (8 fwd, 8 bwd) x 512 threads (8 waves).
//   Wave w owns 32 states; T held as MFMA A-fragments in bf16 hi/lo split
//   (128 regs -> AGPRs, verified no-spill in round 2).
//   Carry (16 b x 256 k) in LDS, double-buffered, bf16 hi/lo planes.
//   KSTR=264 bf16 (528 B = 33x16B granules, 33 odd -> within each 8-lane
//   b128 phase group granule-bank = m mod 8, all distinct -> conflict-free;
//   round-2's 288 gave 36 granules == 4 mod 8 -> 4-way, 5.76M conflict cyc).
//   Per-step barrier: s_waitcnt lgkmcnt(0); s_barrier (vmcnt stays in
//   flight). Global stores staged via dedicated regs so the store-source
//   hazard gets a full step of slack.
//   3-product split MFMA (hh + hl + lh) ~ fp32 precision per step.
// Kernel 2 (score): 512 blocks x 256 threads; wave = n-tile; p = fw*g
//   staged in LDS hi/lo at stride 264.

typedef __bf16 bf16x8 __attribute__((ext_vector_type(8)));
typedef __bf16 bf16x4 __attribute__((ext_vector_type(4)));
typedef float  f32x4  __attribute__((ext_vector_type(4)));

#define LL 256
#define BB 128
#define SS 256
#define BT 16
#define KSTR 264   // carry row stride in bf16: 528 B = 33 granules (odd) -> conflict-free

static __device__ __forceinline__ f32x4 mfma16(bf16x8 a, bf16x8 b, f32x4 c) {
  return __builtin_amdgcn_mfma_f32_16x16x32_bf16(a, b, c, 0, 0, 0);
}

// LDS-only barrier: order ds ops, leave vmcnt in flight.
static __device__ __forceinline__ void lds_barrier() {
  __asm__ __volatile__("s_waitcnt lgkmcnt(0)\n\ts_barrier" ::: "memory");
}

__global__ __launch_bounds__(512, 2)
void hmm_chain(const int* __restrict__ sent, const float* __restrict__ emb,
               const float* __restrict__ T, float* __restrict__ fwbuf,
               float* __restrict__ gbuf)
{
  __shared__ __bf16 s_carry[2][2][BT][KSTR]; // [buf][hi/lo][batch][k]
  __shared__ int s_tok[BT * 257];            // [batch][l], stride 257

  const int tid  = threadIdx.x;
  const int lane = tid & 63;
  const int w    = tid >> 6;   // wave 0..7 -> states [32w, 32w+32)
  const int m    = lane & 15;  // A row-in-tile / B col (= batch)
  const int q    = lane >> 4;  // quad

  const int  bid = blockIdx.x;
  const bool fwd = (bid < 8);
  const int  bg0 = (fwd ? bid : bid - 8) * BT;
  float* const obuf = fwd ? fwbuf : gbuf;

  // ---- stage sentence tokens ----
  for (int idx = tid; idx < BT * LL; idx += 512) {
    int bb = idx >> 8, l2 = idx & 255;
    s_tok[bb * 257 + l2] = sent[(bg0 + bb) * LL + l2];
  }
  __syncthreads();

  // ---- load T fragments (A operand), split bf16 hi/lo: 32 frags = 128 regs
  bf16x8 a_hi[2][8], a_lo[2][8];
#pragma unroll
  for (int mt = 0; mt < 2; ++mt) {
#pragma unroll
    for (int kt = 0; kt < 8; ++kt) {
      const int r0 = 32 * w + 16 * mt + m;   // state (M index)
      const int kb = 32 * kt + 8 * q;        // k base
      float v[8];
      if (fwd) {
        f32x4 f0 = *(const f32x4*)(T + r0 * 256 + kb);
        f32x4 f1 = *(const f32x4*)(T + r0 * 256 + kb + 4);
#pragma unroll
        for (int j = 0; j < 4; ++j) { v[j] = f0[j]; v[4 + j] = f1[j]; }
      } else {
#pragma unroll
        for (int j = 0; j < 8; ++j) v[j] = T[(kb + j) * 256 + r0]; // T^T
      }
      bf16x8 hi, lo;
#pragma unroll
      for (int j = 0; j < 8; ++j) {
        __bf16 h = (__bf16)v[j];
        hi[j] = h;
        lo[j] = (__bf16)(v[j] - (float)h);
      }
      a_hi[mt][kt] = hi; a_lo[mt][kt] = lo;
    }
  }

  // ---- init carry at l0 ----
  const int l0 = fwd ? 0 : (LL - 1);
  {
    const int tok0 = s_tok[m * 257 + l0];
#pragma unroll
    for (int mt = 0; mt < 2; ++mt) {
      const int st = 32 * w + 16 * mt + 4 * q;
      f32x4 e0 = *(const f32x4*)(emb + (size_t)tok0 * 256 + st);
      f32x4 outv = e0;
      if (!fwd) outv = 1.0f;  // g[L-1] = 1
      *(f32x4*)(obuf + ((size_t)(l0 * BB + bg0 + m)) * 256 + st) = outv;
      bf16x4 h4, l4;
#pragma unroll
      for (int r = 0; r < 4; ++r) {
        __bf16 h = (__bf16)e0[r];
        h4[r] = h;
        l4[r] = (__bf16)(e0[r] - (float)h);
      }
      *(bf16x4*)&s_carry[0][0][m][st] = h4;
      *(bf16x4*)&s_carry[0][1][m][st] = l4;
    }
  }

  // ---- prefetch em for first step ----
  f32x4 em_pref[2];
  {
    const int l1 = fwd ? 1 : (LL - 2);
    const int tok1 = s_tok[m * 257 + l1];
#pragma unroll
    for (int mt = 0; mt < 2; ++mt)
      em_pref[mt] = *(const f32x4*)(emb + (size_t)tok1 * 256 + 32 * w + 16 * mt + 4 * q);
  }
  __syncthreads();

  // ---- main chain ----
  for (int s = 1; s < LL; ++s) {
    const int l  = fwd ? s : (LL - 1) - s;
    const int rb = (s - 1) & 1, wb = s & 1;

    // B hi-plane preloaded (32 VGPR); lo-plane streamed inside the loop
    bf16x8 bhi[8];
#pragma unroll
    for (int kt = 0; kt < 8; ++kt)
      bhi[kt] = *(const bf16x8*)&s_carry[rb][0][m][32 * kt + 8 * q];

    f32x4 acc[2];
#pragma unroll
    for (int mt = 0; mt < 2; ++mt) acc[mt] = 0.0f;
#pragma unroll
    for (int kt = 0; kt < 8; ++kt) {
      bf16x8 blo = *(const bf16x8*)&s_carry[rb][1][m][32 * kt + 8 * q];
#pragma unroll
      for (int mt = 0; mt < 2; ++mt) {
        acc[mt] = mfma16(a_hi[mt][kt], bhi[kt], acc[mt]);
        acc[mt] = mfma16(a_hi[mt][kt], blo,     acc[mt]);
        acc[mt] = mfma16(a_lo[mt][kt], bhi[kt], acc[mt]);
      }
    }

    // consume prefetched em, then issue next prefetch
    f32x4 em_now[2];
#pragma unroll
    for (int mt = 0; mt < 2; ++mt) em_now[mt] = em_pref[mt];
    {
      const int ln = fwd ? (s + 1 < LL ? s + 1 : LL - 1)
                         : ((LL - 2) - s > 0 ? (LL - 2) - s : 0);
      const int tokn = s_tok[m * 257 + ln];
#pragma unroll
      for (int mt = 0; mt < 2; ++mt)
        em_pref[mt] = *(const f32x4*)(emb + (size_t)tokn * 256 + 32 * w + 16 * mt + 4 * q);
    }

    // epilogue: scale by em, write LDS carry, then store (staged regs)
    f32x4 sv[2];
#pragma unroll
    for (int mt = 0; mt < 2; ++mt) {
      const int st = 32 * w + 16 * mt + 4 * q;
      f32x4 v  = acc[mt];              // pre-em matmul result
      f32x4 cn = v * em_now[mt];       // new carry
      sv[mt]   = fwd ? cn : v;         // fwd stores fw[l]; bwd stores g[l]=v
      bf16x4 h4, l4;
#pragma unroll
      for (int r = 0; r < 4; ++r) {
        __bf16 h = (__bf16)cn[r];
        h4[r] = h;
        l4[r] = (__bf16)(cn[r] - (float)h);
      }
      *(bf16x4*)&s_carry[wb][0][m][st] = h4;
      *(bf16x4*)&s_carry[wb][1][m][st] = l4;
    }
#pragma unroll
    for (int mt = 0; mt < 2; ++mt) {
      const int st = 32 * w + 16 * mt + 4 * q;
      *(f32x4*)(obuf + ((size_t)(l * BB + bg0 + m)) * 256 + st) = sv[mt];
    }
    lds_barrier();  // LDS ordering only; global stores/loads stay in flight
  }
}

__global__ __launch_bounds__(256, 1)
void hmm_score(const float* __restrict__ fwbuf, const float* __restrict__ gbuf,
               const float* __restrict__ outm, float* __restrict__ score)
{
  __shared__ __bf16 p_hi[64][264];
  __shared__ __bf16 p_lo[64][264];

  const int tid  = threadIdx.x;
  const int lane = tid & 63;
  const int w    = tid >> 6;   // wave = n-tile (labels [16w,16w+16))
  const int m    = lane & 15;
  const int q    = lane >> 4;
  const int R0   = blockIdx.x * 64;  // row = l*128 + b

  // out matrix fragments for THIS wave's n-tile only: 16 frags = 64 VGPR
  bf16x8 o_hi[8], o_lo[8];
#pragma unroll
  for (int kt = 0; kt < 8; ++kt) {
    bf16x8 hi, lo;
#pragma unroll
    for (int j = 0; j < 8; ++j) {
      float vv = outm[(32 * kt + 8 * q + j) * 64 + 16 * w + m];
      __bf16 h = (__bf16)vv;
      hi[j] = h;
      lo[j] = (__bf16)(vv - (float)h);
    }
    o_hi[kt] = hi; o_lo[kt] = lo;
  }

  // stage p = fw * g as split bf16 (coalesced row loads)
  for (int idx = tid; idx < 64 * 64; idx += 256) {
    int row = idx >> 6, c4 = (idx & 63) * 4;
    f32x4 f  = *(const f32x4*)(fwbuf + ((size_t)(R0 + row)) * 256 + c4);
    f32x4 gg = *(const f32x4*)(gbuf  + ((size_t)(R0 + row)) * 256 + c4);
    f32x4 p = f * gg;
    bf16x4 h4, l4;
#pragma unroll
    for (int r = 0; r < 4; ++r) {
      __bf16 h = (__bf16)p[r];
      h4[r] = h;
      l4[r] = (__bf16)(p[r] - (float)h);
    }
    *(bf16x4*)&p_hi[row][c4] = h4;
    *(bf16x4*)&p_lo[row][c4] = l4;
  }
  __syncthreads();

  f32x4 acc[4];
#pragma unroll
  for (int mt = 0; mt < 4; ++mt) acc[mt] = 0.0f;
#pragma unroll
  for (int kt = 0; kt < 8; ++kt) {
#pragma unroll
    for (int mt = 0; mt < 4; ++mt) {
      bf16x8 ph = *(const bf16x8*)&p_hi[16 * mt + m][32 * kt + 8 * q];
      bf16x8 pl = *(const bf16x8*)&p_lo[16 * mt + m][32 * kt + 8 * q];
      acc[mt] = mfma16(ph, o_hi[kt], acc[mt]);
      acc[mt] = mfma16(ph, o_lo[kt], acc[mt]);
      acc[mt] = mfma16(pl, o_hi[kt], acc[mt]);
    }
  }

#pragma unroll
  for (int mt = 0; mt < 4; ++mt) {
#pragma unroll
    for (int r = 0; r < 4; ++r) {
      int row = R0 + 16 * mt + 4 * q + r;
      int l = row >> 7, b = row & 127;
      score[(size_t)b * 16384 + l * 64 + 16 * w + m] = acc[mt][r];
    }
  }
}

extern "C" void kernel_launch(void* const* d_in, const int* in_sizes, int n_in,
                              void* d_out, int out_size, void* d_ws, size_t ws_size,
                              hipStream_t stream) {
  (void)in_sizes; (void)n_in; (void)out_size; (void)ws_size;
  const int*   sent = (const int*)d_in[0];
  const float* emb  = (const float*)d_in[1];
  const float* T    = (const float*)d_in[2];
  const float* outm = (const float*)d_in[3];
  float* fw = (float*)d_ws;                         // [L][B][S] fp32, 32 MB
  float* g  = fw + (size_t)LL * BB * SS;            // [L][B][S] fp32, 32 MB

  hmm_chain<<<16, 512, 0, stream>>>(sent, emb, T, fw, g);
  hmm_score<<<512, 256, 0, stream>>>(fw, g, outm, (float*)d_out);
}

// Round 4
// 420.896 us; speedup vs baseline: 1.2211x; 1.0049x over previous
//
#include <hip/hip_runtime.h>
#include <hip/hip_bf16.h>

// IO-HMM fwd/bwd chain + projection for MI355X (gfx950).
// L=256 steps, B=128 batch, S=256 states, NL=64 labels.
//
// Kernel 1 (chain): 16 blocks (8 fwd, 8 bwd) x 512 threads (8 waves).
//   Wave w owns 32 states; T held as MFMA A-fragments in bf16 hi/lo split.
//   Carry (16 b x 256 k) in LDS, double-buffered, bf16 hi/lo planes.
//   Layout: row stride 264 bf16 (33x16B granules, odd) PLUS xor-swizzle
//   (flip bit2 of 16B-granule column for rows m>=8): conflict-free for both
//   contiguous {0..7} and stride-8 {m in {0,8}, q 0..3} phase groupings.
//   (R3's padding alone left 640 conflict-cyc/step -> stride-8 grouping.)
//   6 independent MFMA accumulator chains (hh/hl/lh x 2 mt, depth 8) --
//   R3's 2 chains of depth 24 exposed ~500+ cyc of dependent-MFMA latency.
//   Per-step barrier: s_waitcnt lgkmcnt(0); s_barrier (vmcnt in flight).
//   3-product split MFMA (hh + hl + lh) ~ fp32 precision per step.
// Kernel 2 (score): 512 blocks x 256 threads. R3 bug: all 4 waves read the
//   IDENTICAL 64 KB of p from LDS. Now wave = (row-half, n-pair): 32 reads
//   per lane instead of 64; o-frags 2 n-tiles = 128 regs; same swizzle.

typedef __bf16 bf16x8 __attribute__((ext_vector_type(8)));
typedef __bf16 bf16x4 __attribute__((ext_vector_type(4)));
typedef float  f32x4  __attribute__((ext_vector_type(4)));

#define LL 256
#define BB 128
#define SS 256
#define BT 16
#define KSTR 264   // carry row stride in bf16 (33 granules, odd)

static __device__ __forceinline__ f32x4 mfma16(bf16x8 a, bf16x8 b, f32x4 c) {
  return __builtin_amdgcn_mfma_f32_16x16x32_bf16(a, b, c, 0, 0, 0);
}

// LDS-only barrier: order ds ops, leave vmcnt in flight.
static __device__ __forceinline__ void lds_barrier() {
  __asm__ __volatile__("s_waitcnt lgkmcnt(0)\n\ts_barrier" ::: "memory");
}

// Swizzled byte offsets into one carry plane (row m, 16B granule col).
// Read: 16B frag at logical k-col granule (4kt+q); flip bit2 for m>=8.
static __device__ __forceinline__ int coff_r(int m, int kt, int q) {
  return m * (KSTR * 2) + (((((kt << 2) + q)) ^ ((m >> 3) << 2)) << 4);
}
// Write: 8B chunk at logical 8B col index col8.
static __device__ __forceinline__ int coff_w(int m, int col8) {
  return m * (KSTR * 2) + ((((col8 >> 1)) ^ ((m >> 3) << 2)) << 4) + ((col8 & 1) << 3);
}

__global__ __launch_bounds__(512, 2)
void hmm_chain(const int* __restrict__ sent, const float* __restrict__ emb,
               const float* __restrict__ T, float* __restrict__ fwbuf,
               float* __restrict__ gbuf)
{
  __shared__ __align__(16) unsigned char s_carry[2][2][BT * KSTR * 2];
  __shared__ int s_tok[BT * 257];            // [batch][l], stride 257

  const int tid  = threadIdx.x;
  const int lane = tid & 63;
  const int w    = tid >> 6;   // wave 0..7 -> states [32w, 32w+32)
  const int m    = lane & 15;  // A row-in-tile / B col (= batch)
  const int q    = lane >> 4;  // quad

  const int  bid = blockIdx.x;
  const bool fwd = (bid < 8);
  const int  bg0 = (fwd ? bid : bid - 8) * BT;
  float* const obuf = fwd ? fwbuf : gbuf;

  // ---- stage sentence tokens ----
  for (int idx = tid; idx < BT * LL; idx += 512) {
    int bb = idx >> 8, l2 = idx & 255;
    s_tok[bb * 257 + l2] = sent[(bg0 + bb) * LL + l2];
  }
  __syncthreads();

  // ---- load T fragments (A operand), split bf16 hi/lo: 32 frags = 128 regs
  bf16x8 a_hi[2][8], a_lo[2][8];
#pragma unroll
  for (int mt = 0; mt < 2; ++mt) {
#pragma unroll
    for (int kt = 0; kt < 8; ++kt) {
      const int r0 = 32 * w + 16 * mt + m;   // state (M index)
      const int kb = 32 * kt + 8 * q;        // k base
      float v[8];
      if (fwd) {
        f32x4 f0 = *(const f32x4*)(T + r0 * 256 + kb);
        f32x4 f1 = *(const f32x4*)(T + r0 * 256 + kb + 4);
#pragma unroll
        for (int j = 0; j < 4; ++j) { v[j] = f0[j]; v[4 + j] = f1[j]; }
      } else {
#pragma unroll
        for (int j = 0; j < 8; ++j) v[j] = T[(kb + j) * 256 + r0]; // T^T
      }
      bf16x8 hi, lo;
#pragma unroll
      for (int j = 0; j < 8; ++j) {
        __bf16 h = (__bf16)v[j];
        hi[j] = h;
        lo[j] = (__bf16)(v[j] - (float)h);
      }
      a_hi[mt][kt] = hi; a_lo[mt][kt] = lo;
    }
  }

  // ---- init carry at l0 ----
  const int l0 = fwd ? 0 : (LL - 1);
  {
    const int tok0 = s_tok[m * 257 + l0];
#pragma unroll
    for (int mt = 0; mt < 2; ++mt) {
      const int st = 32 * w + 16 * mt + 4 * q;
      f32x4 e0 = *(const f32x4*)(emb + (size_t)tok0 * 256 + st);
      f32x4 outv = e0;
      if (!fwd) outv = 1.0f;  // g[L-1] = 1
      *(f32x4*)(obuf + ((size_t)(l0 * BB + bg0 + m)) * 256 + st) = outv;
      bf16x4 h4, l4;
#pragma unroll
      for (int r = 0; r < 4; ++r) {
        __bf16 h = (__bf16)e0[r];
        h4[r] = h;
        l4[r] = (__bf16)(e0[r] - (float)h);
      }
      const int c8 = 8 * w + 4 * mt + q;  // st*2/8
      *(bf16x4*)(&s_carry[0][0][0] + coff_w(m, c8)) = h4;
      *(bf16x4*)(&s_carry[0][1][0] + coff_w(m, c8)) = l4;
    }
  }

  // ---- prefetch em for first step ----
  f32x4 em_pref[2];
  {
    const int l1 = fwd ? 1 : (LL - 2);
    const int tok1 = s_tok[m * 257 + l1];
#pragma unroll
    for (int mt = 0; mt < 2; ++mt)
      em_pref[mt] = *(const f32x4*)(emb + (size_t)tok1 * 256 + 32 * w + 16 * mt + 4 * q);
  }
  __syncthreads();

  // ---- main chain ----
  for (int s = 1; s < LL; ++s) {
    const int l  = fwd ? s : (LL - 1) - s;
    const int rb = (s - 1) & 1, wb = s & 1;

    const unsigned char* phr = &s_carry[rb][0][0];
    const unsigned char* plr = &s_carry[rb][1][0];

    bf16x8 bhi[8], blo[8];
#pragma unroll
    for (int kt = 0; kt < 8; ++kt) {
      bhi[kt] = *(const bf16x8*)(phr + coff_r(m, kt, q));
      blo[kt] = *(const bf16x8*)(plr + coff_r(m, kt, q));
    }

    // 6 independent accumulator chains (depth 8 each)
    f32x4 hh0 = 0.0f, hl0 = 0.0f, lh0 = 0.0f;
    f32x4 hh1 = 0.0f, hl1 = 0.0f, lh1 = 0.0f;
#pragma unroll
    for (int kt = 0; kt < 8; ++kt) {
      hh0 = mfma16(a_hi[0][kt], bhi[kt], hh0);
      hh1 = mfma16(a_hi[1][kt], bhi[kt], hh1);
      hl0 = mfma16(a_hi[0][kt], blo[kt], hl0);
      hl1 = mfma16(a_hi[1][kt], blo[kt], hl1);
      lh0 = mfma16(a_lo[0][kt], bhi[kt], lh0);
      lh1 = mfma16(a_lo[1][kt], bhi[kt], lh1);
    }
    f32x4 acc[2];
    acc[0] = (hh0 + hl0) + lh0;
    acc[1] = (hh1 + hl1) + lh1;

    // consume prefetched em, then issue next prefetch
    f32x4 em_now[2];
#pragma unroll
    for (int mt = 0; mt < 2; ++mt) em_now[mt] = em_pref[mt];
    {
      const int ln = fwd ? (s + 1 < LL ? s + 1 : LL - 1)
                         : ((LL - 2) - s > 0 ? (LL - 2) - s : 0);
      const int tokn = s_tok[m * 257 + ln];
#pragma unroll
      for (int mt = 0; mt < 2; ++mt)
        em_pref[mt] = *(const f32x4*)(emb + (size_t)tokn * 256 + 32 * w + 16 * mt + 4 * q);
    }

    // epilogue: scale by em, write LDS carry, then store (staged regs)
    unsigned char* phw = &s_carry[wb][0][0];
    unsigned char* plw = &s_carry[wb][1][0];
    f32x4 sv[2];
#pragma unroll
    for (int mt = 0; mt < 2; ++mt) {
      f32x4 v  = acc[mt];              // pre-em matmul result
      f32x4 cn = v * em_now[mt];       // new carry
      sv[mt]   = fwd ? cn : v;         // fwd stores fw[l]; bwd stores g[l]=v
      bf16x4 h4, l4;
#pragma unroll
      for (int r = 0; r < 4; ++r) {
        __bf16 h = (__bf16)cn[r];
        h4[r] = h;
        l4[r] = (__bf16)(cn[r] - (float)h);
      }
      const int c8 = 8 * w + 4 * mt + q;
      *(bf16x4*)(phw + coff_w(m, c8)) = h4;
      *(bf16x4*)(plw + coff_w(m, c8)) = l4;
    }
#pragma unroll
    for (int mt = 0; mt < 2; ++mt) {
      const int st = 32 * w + 16 * mt + 4 * q;
      *(f32x4*)(obuf + ((size_t)(l * BB + bg0 + m)) * 256 + st) = sv[mt];
    }
    lds_barrier();  // LDS ordering only; global stores/loads stay in flight
  }
}

__global__ __launch_bounds__(256, 2)
void hmm_score(const float* __restrict__ fwbuf, const float* __restrict__ gbuf,
               const float* __restrict__ outm, float* __restrict__ score)
{
  __shared__ __align__(16) unsigned char p_hi[64 * KSTR * 2];
  __shared__ __align__(16) unsigned char p_lo[64 * KSTR * 2];

  const int tid  = threadIdx.x;
  const int lane = tid & 63;
  const int w    = tid >> 6;
  const int rh   = w >> 1;     // row half: rows [32rh, 32rh+32)
  const int np   = w & 1;      // n-pair: n-tiles {2np, 2np+1}
  const int m    = lane & 15;
  const int q    = lane >> 4;
  const int R0   = blockIdx.x * 64;  // row = l*128 + b

  // out-matrix fragments for this wave's 2 n-tiles: 32 frags = 128 regs
  bf16x8 o_hi[8][2], o_lo[8][2];
#pragma unroll
  for (int kt = 0; kt < 8; ++kt) {
#pragma unroll
    for (int jn = 0; jn < 2; ++jn) {
      bf16x8 hi, lo;
#pragma unroll
      for (int j = 0; j < 8; ++j) {
        float vv = outm[(32 * kt + 8 * q + j) * 64 + 16 * (2 * np + jn) + m];
        __bf16 h = (__bf16)vv;
        hi[j] = h;
        lo[j] = (__bf16)(vv - (float)h);
      }
      o_hi[kt][jn] = hi; o_lo[kt][jn] = lo;
    }
  }

  // stage p = fw * g as split bf16 (coalesced row loads), swizzled layout
  for (int idx = tid; idx < 64 * 64; idx += 256) {
    int row = idx >> 6, c = idx & 63;       // c = 8B column index
    f32x4 f  = *(const f32x4*)(fwbuf + ((size_t)(R0 + row)) * 256 + c * 4);
    f32x4 gg = *(const f32x4*)(gbuf  + ((size_t)(R0 + row)) * 256 + c * 4);
    f32x4 p = f * gg;
    bf16x4 h4, l4;
#pragma unroll
    for (int r = 0; r < 4; ++r) {
      __bf16 h = (__bf16)p[r];
      h4[r] = h;
      l4[r] = (__bf16)(p[r] - (float)h);
    }
    *(bf16x4*)(p_hi + coff_w(row, c)) = h4;
    *(bf16x4*)(p_lo + coff_w(row, c)) = l4;
  }
  lds_barrier();

  f32x4 acc[2][2];
#pragma unroll
  for (int j = 0; j < 2; ++j)
#pragma unroll
    for (int jn = 0; jn < 2; ++jn) acc[j][jn] = 0.0f;

#pragma unroll
  for (int kt = 0; kt < 8; ++kt) {
#pragma unroll
    for (int j = 0; j < 2; ++j) {
      const int row = 32 * rh + 16 * j + m;
      bf16x8 ph = *(const bf16x8*)(p_hi + coff_r(row, kt, q));
      bf16x8 pl = *(const bf16x8*)(p_lo + coff_r(row, kt, q));
#pragma unroll
      for (int jn = 0; jn < 2; ++jn) {
        acc[j][jn] = mfma16(ph, o_hi[kt][jn], acc[j][jn]);
        acc[j][jn] = mfma16(ph, o_lo[kt][jn], acc[j][jn]);
        acc[j][jn] = mfma16(pl, o_hi[kt][jn], acc[j][jn]);
      }
    }
  }

#pragma unroll
  for (int j = 0; j < 2; ++j) {
#pragma unroll
    for (int jn = 0; jn < 2; ++jn) {
#pragma unroll
      for (int r = 0; r < 4; ++r) {
        int row = R0 + 32 * rh + 16 * j + 4 * q + r;
        int l = row >> 7, b = row & 127;
        score[(size_t)b * 16384 + l * 64 + 16 * (2 * np + jn) + m] = acc[j][jn][r];
      }
    }
  }
}

extern "C" void kernel_launch(void* const* d_in, const int* in_sizes, int n_in,
                              void* d_out, int out_size, void* d_ws, size_t ws_size,
                              hipStream_t stream) {
  (void)in_sizes; (void)n_in; (void)out_size; (void)ws_size;
  const int*   sent = (const int*)d_in[0];
  const float* emb  = (const float*)d_in[1];
  const float* T    = (const float*)d_in[2];
  const float* outm = (const float*)d_in[3];
  float* fw = (float*)d_ws;                         // [L][B][S] fp32, 32 MB
  float* g  = fw + (size_t)LL * BB * SS;            // [L][B][S] fp32, 32 MB

  hmm_chain<<<16, 512, 0, stream>>>(sent, emb, T, fw, g);
  hmm_score<<<512, 256, 0, stream>>>(fw, g, outm, (float*)d_out);
}

// Round 5
// 399.302 us; speedup vs baseline: 1.2871x; 1.0541x over previous
//
#include <hip/hip_runtime.h>
#include <hip/hip_bf16.h>

// IO-HMM fwd/bwd chain + projection for MI355X (gfx950).
// L=256 steps, B=128 batch, S=256 states, NL=64 labels.
//
// Kernel 1 (chain): 16 blocks (8 fwd, 8 bwd) x 512 threads (8 waves).
//   Wave w owns 32 states; T held as MFMA A-fragments in bf16 hi/lo split.
//   Carry (16 b x 256 k) in LDS, double-buffered, bf16 hi/lo planes.
//   Layout: row stride = 536 B = 67 x 8B (ODD in 8B units). All carry
//   accesses are b64 (8B-aligned): pair-bank = (3m + 2q + 8kt) mod 16 is
//   perfectly uniform (4 lanes/pair = minimum) for any phase grouping.
//   History: R2 stride 576B -> 1411 conflict-cyc/step; R3 528B -> 640
//   (every address even-8B -> half the bank-pairs); R4 xor -> 1152 (worse,
//   model falsified). Odd-8B stride is the only parity-complete fix.
//   6 independent MFMA accumulator chains (hh/hl/lh x 2 mt, depth 8).
//   Per-step barrier: s_waitcnt lgkmcnt(0); s_barrier (vmcnt in flight).
//   3-product split MFMA (hh + hl + lh) ~ fp32 precision per step.
// Kernel 2 (score): 512 blocks x 256 threads; wave = (row-half, n-pair);
//   p = fw*g staged in LDS hi/lo, same odd-8B layout.

typedef __bf16 bf16x8 __attribute__((ext_vector_type(8)));
typedef __bf16 bf16x4 __attribute__((ext_vector_type(4)));
typedef float  f32x4  __attribute__((ext_vector_type(4)));
typedef unsigned long long u64;

#define LL 256
#define BB 128
#define SS 256
#define BT 16
#define RSTR8 67   // carry row stride in 8B units (ODD -> full bank-pair coverage)

static __device__ __forceinline__ f32x4 mfma16(bf16x8 a, bf16x8 b, f32x4 c) {
  return __builtin_amdgcn_mfma_f32_16x16x32_bf16(a, b, c, 0, 0, 0);
}

// LDS-only barrier: order ds ops, leave vmcnt in flight.
static __device__ __forceinline__ void lds_barrier() {
  __asm__ __volatile__("s_waitcnt lgkmcnt(0)\n\ts_barrier" ::: "memory");
}

// B fragment (16B logical) read as two b64 halves (8B-aligned layout).
static __device__ __forceinline__ bf16x8 read_frag(const u64* plane, int m, int kt, int q) {
  const int o = m * RSTR8 + kt * 8 + q * 2;
  union { u64 u[2]; bf16x8 v; } x;
  x.u[0] = plane[o];
  x.u[1] = plane[o + 1];
  return x.v;
}

// 8B carry write at logical 8B column c8.
static __device__ __forceinline__ void write_h4(u64* plane, int m, int c8, bf16x4 h) {
  union { bf16x4 v; u64 u; } x;
  x.v = h;
  plane[m * RSTR8 + c8] = x.u;
}

__global__ __launch_bounds__(512, 2)
void hmm_chain(const int* __restrict__ sent, const float* __restrict__ emb,
               const float* __restrict__ T, float* __restrict__ fwbuf,
               float* __restrict__ gbuf)
{
  __shared__ u64 s_carry[2][2][BT * RSTR8]; // [buf][hi/lo][row*stride]
  __shared__ int s_tok[BT * 257];           // [batch][l], stride 257

  const int tid  = threadIdx.x;
  const int lane = tid & 63;
  const int w    = tid >> 6;   // wave 0..7 -> states [32w, 32w+32)
  const int m    = lane & 15;  // A row-in-tile / B col (= batch)
  const int q    = lane >> 4;  // quad

  const int  bid = blockIdx.x;
  const bool fwd = (bid < 8);
  const int  bg0 = (fwd ? bid : bid - 8) * BT;
  float* const obuf = fwd ? fwbuf : gbuf;

  // ---- stage sentence tokens ----
  for (int idx = tid; idx < BT * LL; idx += 512) {
    int bb = idx >> 8, l2 = idx & 255;
    s_tok[bb * 257 + l2] = sent[(bg0 + bb) * LL + l2];
  }
  __syncthreads();

  // ---- load T fragments (A operand), split bf16 hi/lo: 32 frags = 128 regs
  bf16x8 a_hi[2][8], a_lo[2][8];
#pragma unroll
  for (int mt = 0; mt < 2; ++mt) {
#pragma unroll
    for (int kt = 0; kt < 8; ++kt) {
      const int r0 = 32 * w + 16 * mt + m;   // state (M index)
      const int kb = 32 * kt + 8 * q;        // k base
      float v[8];
      if (fwd) {
        f32x4 f0 = *(const f32x4*)(T + r0 * 256 + kb);
        f32x4 f1 = *(const f32x4*)(T + r0 * 256 + kb + 4);
#pragma unroll
        for (int j = 0; j < 4; ++j) { v[j] = f0[j]; v[4 + j] = f1[j]; }
      } else {
#pragma unroll
        for (int j = 0; j < 8; ++j) v[j] = T[(kb + j) * 256 + r0]; // T^T
      }
      bf16x8 hi, lo;
#pragma unroll
      for (int j = 0; j < 8; ++j) {
        __bf16 h = (__bf16)v[j];
        hi[j] = h;
        lo[j] = (__bf16)(v[j] - (float)h);
      }
      a_hi[mt][kt] = hi; a_lo[mt][kt] = lo;
    }
  }

  // ---- init carry at l0 ----
  const int l0 = fwd ? 0 : (LL - 1);
  {
    const int tok0 = s_tok[m * 257 + l0];
#pragma unroll
    for (int mt = 0; mt < 2; ++mt) {
      const int st = 32 * w + 16 * mt + 4 * q;
      f32x4 e0 = *(const f32x4*)(emb + (size_t)tok0 * 256 + st);
      f32x4 outv = e0;
      if (!fwd) outv = 1.0f;  // g[L-1] = 1
      *(f32x4*)(obuf + ((size_t)(l0 * BB + bg0 + m)) * 256 + st) = outv;
      bf16x4 h4, l4;
#pragma unroll
      for (int r = 0; r < 4; ++r) {
        __bf16 h = (__bf16)e0[r];
        h4[r] = h;
        l4[r] = (__bf16)(e0[r] - (float)h);
      }
      const int c8 = 8 * w + 4 * mt + q;  // st/4
      write_h4(&s_carry[0][0][0], m, c8, h4);
      write_h4(&s_carry[0][1][0], m, c8, l4);
    }
  }

  // ---- prefetch em for first step ----
  f32x4 em_pref[2];
  {
    const int l1 = fwd ? 1 : (LL - 2);
    const int tok1 = s_tok[m * 257 + l1];
#pragma unroll
    for (int mt = 0; mt < 2; ++mt)
      em_pref[mt] = *(const f32x4*)(emb + (size_t)tok1 * 256 + 32 * w + 16 * mt + 4 * q);
  }
  __syncthreads();

  // ---- main chain ----
  for (int s = 1; s < LL; ++s) {
    const int l  = fwd ? s : (LL - 1) - s;
    const int rb = (s - 1) & 1, wb = s & 1;

    const u64* phr = &s_carry[rb][0][0];
    const u64* plr = &s_carry[rb][1][0];

    bf16x8 bhi[8], blo[8];
#pragma unroll
    for (int kt = 0; kt < 8; ++kt) {
      bhi[kt] = read_frag(phr, m, kt, q);
      blo[kt] = read_frag(plr, m, kt, q);
    }

    // 6 independent accumulator chains (depth 8 each)
    f32x4 hh0 = 0.0f, hl0 = 0.0f, lh0 = 0.0f;
    f32x4 hh1 = 0.0f, hl1 = 0.0f, lh1 = 0.0f;
#pragma unroll
    for (int kt = 0; kt < 8; ++kt) {
      hh0 = mfma16(a_hi[0][kt], bhi[kt], hh0);
      hh1 = mfma16(a_hi[1][kt], bhi[kt], hh1);
      hl0 = mfma16(a_hi[0][kt], blo[kt], hl0);
      hl1 = mfma16(a_hi[1][kt], blo[kt], hl1);
      lh0 = mfma16(a_lo[0][kt], bhi[kt], lh0);
      lh1 = mfma16(a_lo[1][kt], bhi[kt], lh1);
    }
    f32x4 acc[2];
    acc[0] = (hh0 + hl0) + lh0;
    acc[1] = (hh1 + hl1) + lh1;

    // consume prefetched em, then issue next prefetch
    f32x4 em_now[2];
#pragma unroll
    for (int mt = 0; mt < 2; ++mt) em_now[mt] = em_pref[mt];
    {
      const int ln = fwd ? (s + 1 < LL ? s + 1 : LL - 1)
                         : ((LL - 2) - s > 0 ? (LL - 2) - s : 0);
      const int tokn = s_tok[m * 257 + ln];
#pragma unroll
      for (int mt = 0; mt < 2; ++mt)
        em_pref[mt] = *(const f32x4*)(emb + (size_t)tokn * 256 + 32 * w + 16 * mt + 4 * q);
    }

    // epilogue: scale by em, write LDS carry, then store (staged regs)
    u64* phw = &s_carry[wb][0][0];
    u64* plw = &s_carry[wb][1][0];
    f32x4 sv[2];
#pragma unroll
    for (int mt = 0; mt < 2; ++mt) {
      f32x4 v  = acc[mt];              // pre-em matmul result
      f32x4 cn = v * em_now[mt];       // new carry
      sv[mt]   = fwd ? cn : v;         // fwd stores fw[l]; bwd stores g[l]=v
      bf16x4 h4, l4;
#pragma unroll
      for (int r = 0; r < 4; ++r) {
        __bf16 h = (__bf16)cn[r];
        h4[r] = h;
        l4[r] = (__bf16)(cn[r] - (float)h);
      }
      const int c8 = 8 * w + 4 * mt + q;
      write_h4(phw, m, c8, h4);
      write_h4(plw, m, c8, l4);
    }
#pragma unroll
    for (int mt = 0; mt < 2; ++mt) {
      const int st = 32 * w + 16 * mt + 4 * q;
      *(f32x4*)(obuf + ((size_t)(l * BB + bg0 + m)) * 256 + st) = sv[mt];
    }
    lds_barrier();  // LDS ordering only; global stores/loads stay in flight
  }
}

__global__ __launch_bounds__(256, 2)
void hmm_score(const float* __restrict__ fwbuf, const float* __restrict__ gbuf,
               const float* __restrict__ outm, float* __restrict__ score)
{
  __shared__ u64 p_hi[64 * RSTR8];
  __shared__ u64 p_lo[64 * RSTR8];

  const int tid  = threadIdx.x;
  const int lane = tid & 63;
  const int w    = tid >> 6;
  const int rh   = w >> 1;     // row half: rows [32rh, 32rh+32)
  const int np   = w & 1;      // n-pair: n-tiles {2np, 2np+1}
  const int m    = lane & 15;
  const int q    = lane >> 4;
  const int R0   = blockIdx.x * 64;  // row = l*128 + b

  // out-matrix fragments for this wave's 2 n-tiles: 32 frags = 128 regs
  bf16x8 o_hi[8][2], o_lo[8][2];
#pragma unroll
  for (int kt = 0; kt < 8; ++kt) {
#pragma unroll
    for (int jn = 0; jn < 2; ++jn) {
      bf16x8 hi, lo;
#pragma unroll
      for (int j = 0; j < 8; ++j) {
        float vv = outm[(32 * kt + 8 * q + j) * 64 + 16 * (2 * np + jn) + m];
        __bf16 h = (__bf16)vv;
        hi[j] = h;
        lo[j] = (__bf16)(vv - (float)h);
      }
      o_hi[kt][jn] = hi; o_lo[kt][jn] = lo;
    }
  }

  // stage p = fw * g as split bf16 (coalesced row loads)
  for (int idx = tid; idx < 64 * 64; idx += 256) {
    int row = idx >> 6, c = idx & 63;       // c = 8B column index
    f32x4 f  = *(const f32x4*)(fwbuf + ((size_t)(R0 + row)) * 256 + c * 4);
    f32x4 gg = *(const f32x4*)(gbuf  + ((size_t)(R0 + row)) * 256 + c * 4);
    f32x4 p = f * gg;
    bf16x4 h4, l4;
#pragma unroll
    for (int r = 0; r < 4; ++r) {
      __bf16 h = (__bf16)p[r];
      h4[r] = h;
      l4[r] = (__bf16)(p[r] - (float)h);
    }
    write_h4(p_hi, row, c, h4);
    write_h4(p_lo, row, c, l4);
  }
  lds_barrier();

  f32x4 acc[2][2];
#pragma unroll
  for (int j = 0; j < 2; ++j)
#pragma unroll
    for (int jn = 0; jn < 2; ++jn) acc[j][jn] = 0.0f;

#pragma unroll
  for (int kt = 0; kt < 8; ++kt) {
#pragma unroll
    for (int j = 0; j < 2; ++j) {
      const int row = 32 * rh + 16 * j + m;
      bf16x8 ph = read_frag(p_hi, row, kt, q);
      bf16x8 pl = read_frag(p_lo, row, kt, q);
#pragma unroll
      for (int jn = 0; jn < 2; ++jn) {
        acc[j][jn] = mfma16(ph, o_hi[kt][jn], acc[j][jn]);
        acc[j][jn] = mfma16(ph, o_lo[kt][jn], acc[j][jn]);
        acc[j][jn] = mfma16(pl, o_hi[kt][jn], acc[j][jn]);
      }
    }
  }

#pragma unroll
  for (int j = 0; j < 2; ++j) {
#pragma unroll
    for (int jn = 0; jn < 2; ++jn) {
#pragma unroll
      for (int r = 0; r < 4; ++r) {
        int row = R0 + 32 * rh + 16 * j + 4 * q + r;
        int l = row >> 7, b = row & 127;
        score[(size_t)b * 16384 + l * 64 + 16 * (2 * np + jn) + m] = acc[j][jn][r];
      }
    }
  }
}

extern "C" void kernel_launch(void* const* d_in, const int* in_sizes, int n_in,
                              void* d_out, int out_size, void* d_ws, size_t ws_size,
                              hipStream_t stream) {
  (void)in_sizes; (void)n_in; (void)out_size; (void)ws_size;
  const int*   sent = (const int*)d_in[0];
  const float* emb  = (const float*)d_in[1];
  const float* T    = (const float*)d_in[2];
  const float* outm = (const float*)d_in[3];
  float* fw = (float*)d_ws;                         // [L][B][S] fp32, 32 MB
  float* g  = fw + (size_t)LL * BB * SS;            // [L][B][S] fp32, 32 MB

  hmm_chain<<<16, 512, 0, stream>>>(sent, emb, T, fw, g);
  hmm_score<<<512, 256, 0, stream>>>(fw, g, outm, (float*)d_out);
}

// Round 6
// 325.070 us; speedup vs baseline: 1.5810x; 1.2284x over previous
//
#include <hip/hip_runtime.h>
#include <hip/hip_bf16.h>

// IO-HMM fwd/bwd chain + projection for MI355X (gfx950).
// L=256 steps, B=128 batch, S=256 states, NL=64 labels.
//
// Kernel 1 (chain): 16 blocks (8 fwd, 8 bwd) x 512 threads (8 waves).
//   Wave w owns 32 states; T held as MFMA A-fragments in f16:
//     a_hi = f16(T), a_lo = f16((T - a_hi) * 2048)   [scaled: raw lo ~5e-5
//     falls in f16-denormal range and MFMA may flush it]
//   acc = hh + lh * (1/2048)  -> T represented to ~2^-22.
//   Carry (16 b x 256 k) in LDS, double-buffered, SINGLE f16 plane
//   (R5 had bf16 hi/lo = 2 planes; single-f16 halves LDS read volume
//   128->64 KB/CU/step and cuts MFMA 48->32/wave; only error source is
//   carry requantization 2^-12/step, incoherent -> ~0.4%/direction,
//   threshold is 2%).
//   Layout: row stride 67 x 8B (ODD in 8B units) -> 0 bank conflicts
//   (verified R5: SQ_LDS_BANK_CONFLICT went 4.7M -> 0).
//   Per-step barrier: s_waitcnt lgkmcnt(0); s_barrier (vmcnt in flight).
// Kernel 2 (score): unchanged from R5 (bf16 3-product, ~45 us).

typedef _Float16 half8 __attribute__((ext_vector_type(8)));
typedef _Float16 half4 __attribute__((ext_vector_type(4)));
typedef __bf16 bf16x8 __attribute__((ext_vector_type(8)));
typedef __bf16 bf16x4 __attribute__((ext_vector_type(4)));
typedef float  f32x4  __attribute__((ext_vector_type(4)));
typedef unsigned long long u64;

#define LL 256
#define BB 128
#define SS 256
#define BT 16
#define RSTR8 67   // carry row stride in 8B units (ODD -> conflict-free, R5-verified)
#define LO_SCALE 2048.0f
#define LO_UNSCALE 4.8828125e-4f

static __device__ __forceinline__ f32x4 mfma16f(half8 a, half8 b, f32x4 c) {
  return __builtin_amdgcn_mfma_f32_16x16x32_f16(a, b, c, 0, 0, 0);
}
static __device__ __forceinline__ f32x4 mfma16(bf16x8 a, bf16x8 b, f32x4 c) {
  return __builtin_amdgcn_mfma_f32_16x16x32_bf16(a, b, c, 0, 0, 0);
}

// LDS-only barrier: order ds ops, leave vmcnt in flight.
static __device__ __forceinline__ void lds_barrier() {
  __asm__ __volatile__("s_waitcnt lgkmcnt(0)\n\ts_barrier" ::: "memory");
}

// 16B logical fragment read as two b64 halves (8B-aligned odd-stride layout).
static __device__ __forceinline__ half8 read_frag_h(const u64* plane, int m, int kt, int q) {
  const int o = m * RSTR8 + kt * 8 + q * 2;
  union { u64 u[2]; half8 v; } x;
  x.u[0] = plane[o];
  x.u[1] = plane[o + 1];
  return x.v;
}
static __device__ __forceinline__ bf16x8 read_frag_b(const u64* plane, int m, int kt, int q) {
  const int o = m * RSTR8 + kt * 8 + q * 2;
  union { u64 u[2]; bf16x8 v; } x;
  x.u[0] = plane[o];
  x.u[1] = plane[o + 1];
  return x.v;
}

// 8B write at logical 8B column c8.
static __device__ __forceinline__ void write_h4f(u64* plane, int m, int c8, half4 h) {
  union { half4 v; u64 u; } x;
  x.v = h;
  plane[m * RSTR8 + c8] = x.u;
}
static __device__ __forceinline__ void write_h4b(u64* plane, int m, int c8, bf16x4 h) {
  union { bf16x4 v; u64 u; } x;
  x.v = h;
  plane[m * RSTR8 + c8] = x.u;
}

__global__ __launch_bounds__(512, 2)
void hmm_chain(const int* __restrict__ sent, const float* __restrict__ emb,
               const float* __restrict__ T, float* __restrict__ fwbuf,
               float* __restrict__ gbuf)
{
  __shared__ u64 s_carry[2][BT * RSTR8]; // [buf][row*stride], single f16 plane
  __shared__ int s_tok[BT * 257];        // [batch][l], stride 257

  const int tid  = threadIdx.x;
  const int lane = tid & 63;
  const int w    = tid >> 6;   // wave 0..7 -> states [32w, 32w+32)
  const int m    = lane & 15;  // A row-in-tile / B col (= batch)
  const int q    = lane >> 4;  // quad

  const int  bid = blockIdx.x;
  const bool fwd = (bid < 8);
  const int  bg0 = (fwd ? bid : bid - 8) * BT;
  float* const obuf = fwd ? fwbuf : gbuf;

  // ---- stage sentence tokens ----
  for (int idx = tid; idx < BT * LL; idx += 512) {
    int bb = idx >> 8, l2 = idx & 255;
    s_tok[bb * 257 + l2] = sent[(bg0 + bb) * LL + l2];
  }
  __syncthreads();

  // ---- load T fragments (A operand), f16 hi + scaled-lo: 32 frags = 128 regs
  half8 a_hi[2][8], a_lo[2][8];
#pragma unroll
  for (int mt = 0; mt < 2; ++mt) {
#pragma unroll
    for (int kt = 0; kt < 8; ++kt) {
      const int r0 = 32 * w + 16 * mt + m;   // state (M index)
      const int kb = 32 * kt + 8 * q;        // k base
      float v[8];
      if (fwd) {
        f32x4 f0 = *(const f32x4*)(T + r0 * 256 + kb);
        f32x4 f1 = *(const f32x4*)(T + r0 * 256 + kb + 4);
#pragma unroll
        for (int j = 0; j < 4; ++j) { v[j] = f0[j]; v[4 + j] = f1[j]; }
      } else {
#pragma unroll
        for (int j = 0; j < 8; ++j) v[j] = T[(kb + j) * 256 + r0]; // T^T
      }
      half8 hi, lo;
#pragma unroll
      for (int j = 0; j < 8; ++j) {
        _Float16 h = (_Float16)v[j];
        hi[j] = h;
        lo[j] = (_Float16)((v[j] - (float)h) * LO_SCALE);
      }
      a_hi[mt][kt] = hi; a_lo[mt][kt] = lo;
    }
  }

  // ---- init carry at l0 ----
  const int l0 = fwd ? 0 : (LL - 1);
  {
    const int tok0 = s_tok[m * 257 + l0];
#pragma unroll
    for (int mt = 0; mt < 2; ++mt) {
      const int st = 32 * w + 16 * mt + 4 * q;
      f32x4 e0 = *(const f32x4*)(emb + (size_t)tok0 * 256 + st);
      f32x4 outv = e0;
      if (!fwd) outv = 1.0f;  // g[L-1] = 1
      *(f32x4*)(obuf + ((size_t)(l0 * BB + bg0 + m)) * 256 + st) = outv;
      half4 h4;
#pragma unroll
      for (int r = 0; r < 4; ++r) h4[r] = (_Float16)e0[r];
      const int c8 = 8 * w + 4 * mt + q;  // st/4
      write_h4f(&s_carry[0][0], m, c8, h4);
    }
  }

  // ---- prefetch em for first step ----
  f32x4 em_pref[2];
  {
    const int l1 = fwd ? 1 : (LL - 2);
    const int tok1 = s_tok[m * 257 + l1];
#pragma unroll
    for (int mt = 0; mt < 2; ++mt)
      em_pref[mt] = *(const f32x4*)(emb + (size_t)tok1 * 256 + 32 * w + 16 * mt + 4 * q);
  }
  __syncthreads();

  // ---- main chain ----
  for (int s = 1; s < LL; ++s) {
    const int l  = fwd ? s : (LL - 1) - s;
    const int rb = (s - 1) & 1, wb = s & 1;

    const u64* pr = &s_carry[rb][0];

    half8 bfr[8];
#pragma unroll
    for (int kt = 0; kt < 8; ++kt)
      bfr[kt] = read_frag_h(pr, m, kt, q);

    // 4 independent accumulator chains (depth 8 each)
    f32x4 hh0 = 0.0f, lh0 = 0.0f;
    f32x4 hh1 = 0.0f, lh1 = 0.0f;
#pragma unroll
    for (int kt = 0; kt < 8; ++kt) {
      hh0 = mfma16f(a_hi[0][kt], bfr[kt], hh0);
      hh1 = mfma16f(a_hi[1][kt], bfr[kt], hh1);
      lh0 = mfma16f(a_lo[0][kt], bfr[kt], lh0);
      lh1 = mfma16f(a_lo[1][kt], bfr[kt], lh1);
    }
    f32x4 acc[2];
    acc[0] = hh0 + lh0 * LO_UNSCALE;
    acc[1] = hh1 + lh1 * LO_UNSCALE;

    // consume prefetched em, then issue next prefetch
    f32x4 em_now[2];
#pragma unroll
    for (int mt = 0; mt < 2; ++mt) em_now[mt] = em_pref[mt];
    {
      const int ln = fwd ? (s + 1 < LL ? s + 1 : LL - 1)
                         : ((LL - 2) - s > 0 ? (LL - 2) - s : 0);
      const int tokn = s_tok[m * 257 + ln];
#pragma unroll
      for (int mt = 0; mt < 2; ++mt)
        em_pref[mt] = *(const f32x4*)(emb + (size_t)tokn * 256 + 32 * w + 16 * mt + 4 * q);
    }

    // epilogue: scale by em, write LDS carry (f16), then global store
    u64* pw = &s_carry[wb][0];
    f32x4 sv[2];
#pragma unroll
    for (int mt = 0; mt < 2; ++mt) {
      f32x4 v  = acc[mt];              // pre-em matmul result
      f32x4 cn = v * em_now[mt];       // new carry
      sv[mt]   = fwd ? cn : v;         // fwd stores fw[l]; bwd stores g[l]=v
      half4 h4;
#pragma unroll
      for (int r = 0; r < 4; ++r) h4[r] = (_Float16)cn[r];
      const int c8 = 8 * w + 4 * mt + q;
      write_h4f(pw, m, c8, h4);
    }
#pragma unroll
    for (int mt = 0; mt < 2; ++mt) {
      const int st = 32 * w + 16 * mt + 4 * q;
      *(f32x4*)(obuf + ((size_t)(l * BB + bg0 + m)) * 256 + st) = sv[mt];
    }
    lds_barrier();  // LDS ordering only; global stores/loads stay in flight
  }
}

__global__ __launch_bounds__(256, 2)
void hmm_score(const float* __restrict__ fwbuf, const float* __restrict__ gbuf,
               const float* __restrict__ outm, float* __restrict__ score)
{
  __shared__ u64 p_hi[64 * RSTR8];
  __shared__ u64 p_lo[64 * RSTR8];

  const int tid  = threadIdx.x;
  const int lane = tid & 63;
  const int w    = tid >> 6;
  const int rh   = w >> 1;     // row half: rows [32rh, 32rh+32)
  const int np   = w & 1;      // n-pair: n-tiles {2np, 2np+1}
  const int m    = lane & 15;
  const int q    = lane >> 4;
  const int R0   = blockIdx.x * 64;  // row = l*128 + b

  // out-matrix fragments for this wave's 2 n-tiles: 32 frags = 128 regs
  bf16x8 o_hi[8][2], o_lo[8][2];
#pragma unroll
  for (int kt = 0; kt < 8; ++kt) {
#pragma unroll
    for (int jn = 0; jn < 2; ++jn) {
      bf16x8 hi, lo;
#pragma unroll
      for (int j = 0; j < 8; ++j) {
        float vv = outm[(32 * kt + 8 * q + j) * 64 + 16 * (2 * np + jn) + m];
        __bf16 h = (__bf16)vv;
        hi[j] = h;
        lo[j] = (__bf16)(vv - (float)h);
      }
      o_hi[kt][jn] = hi; o_lo[kt][jn] = lo;
    }
  }

  // stage p = fw * g as split bf16 (coalesced row loads)
  for (int idx = tid; idx < 64 * 64; idx += 256) {
    int row = idx >> 6, c = idx & 63;       // c = 8B column index
    f32x4 f  = *(const f32x4*)(fwbuf + ((size_t)(R0 + row)) * 256 + c * 4);
    f32x4 gg = *(const f32x4*)(gbuf  + ((size_t)(R0 + row)) * 256 + c * 4);
    f32x4 p = f * gg;
    bf16x4 h4, l4;
#pragma unroll
    for (int r = 0; r < 4; ++r) {
      __bf16 h = (__bf16)p[r];
      h4[r] = h;
      l4[r] = (__bf16)(p[r] - (float)h);
    }
    write_h4b(p_hi, row, c, h4);
    write_h4b(p_lo, row, c, l4);
  }
  lds_barrier();

  f32x4 acc[2][2];
#pragma unroll
  for (int j = 0; j < 2; ++j)
#pragma unroll
    for (int jn = 0; jn < 2; ++jn) acc[j][jn] = 0.0f;

#pragma unroll
  for (int kt = 0; kt < 8; ++kt) {
#pragma unroll
    for (int j = 0; j < 2; ++j) {
      const int row = 32 * rh + 16 * j + m;
      bf16x8 ph = read_frag_b(p_hi, row, kt, q);
      bf16x8 pl = read_frag_b(p_lo, row, kt, q);
#pragma unroll
      for (int jn = 0; jn < 2; ++jn) {
        acc[j][jn] = mfma16(ph, o_hi[kt][jn], acc[j][jn]);
        acc[j][jn] = mfma16(ph, o_lo[kt][jn], acc[j][jn]);
        acc[j][jn] = mfma16(pl, o_hi[kt][jn], acc[j][jn]);
      }
    }
  }

#pragma unroll
  for (int j = 0; j < 2; ++j) {
#pragma unroll
    for (int jn = 0; jn < 2; ++jn) {
#pragma unroll
      for (int r = 0; r < 4; ++r) {
        int row = R0 + 32 * rh + 16 * j + 4 * q + r;
        int l = row >> 7, b = row & 127;
        score[(size_t)b * 16384 + l * 64 + 16 * (2 * np + jn) + m] = acc[j][jn][r];
      }
    }
  }
}

extern "C" void kernel_launch(void* const* d_in, const int* in_sizes, int n_in,
                              void* d_out, int out_size, void* d_ws, size_t ws_size,
                              hipStream_t stream) {
  (void)in_sizes; (void)n_in; (void)out_size; (void)ws_size;
  const int*   sent = (const int*)d_in[0];
  const float* emb  = (const float*)d_in[1];
  const float* T    = (const float*)d_in[2];
  const float* outm = (const float*)d_in[3];
  float* fw = (float*)d_ws;                         // [L][B][S] fp32, 32 MB
  float* g  = fw + (size_t)LL * BB * SS;            // [L][B][S] fp32, 32 MB

  hmm_chain<<<16, 512, 0, stream>>>(sent, emb, T, fw, g);
  hmm_score<<<512, 256, 0, stream>>>(fw, g, outm, (float*)d_out);
}